// Round 17
// baseline (165.919 us; speedup 1.0000x reference)
//
#include <hip/hip_runtime.h>
#include <hip/hip_bf16.h>
#include <math.h>

#define TT 2048
#define HH 512   // hidden = NUM_HEADS*DIM_KEY
#define NH 8
#define DK 64
#define WIN 16
#define NC 33    // 2*WIN+1
#define MT 8192  // B*T rows

// ===== MEASUREMENT ROUND: fused body x2 (idempotent) to crack the top-5 ====
#define FUSED_REP 2

typedef __attribute__((ext_vector_type(8))) short bf16x8;
typedef __attribute__((ext_vector_type(4))) float f32x4;

__device__ inline ushort f2bf(float f) {   // RNE float -> bf16 bits
  uint u = __builtin_bit_cast(uint, f);
  return (ushort)((u + 0x7FFFu + ((u >> 16) & 1u)) >> 16);
}
__device__ inline ushort cvt1(float f) {   // compiler cast (v_cvt_pk capable)
  __hip_bfloat16 h = __float2bfloat16(f);
  return __builtin_bit_cast(ushort, h);
}

// ---------------- W fp32 -> bf16 pre-convert (weights only, 2 MB) ---------
__global__ __launch_bounds__(256) void cvt_w(
    const float* __restrict__ Wq, const float* __restrict__ Wk,
    ushort* __restrict__ Wqb, ushort* __restrict__ Wkb)
{
  const int id = blockIdx.x * 256 + threadIdx.x;   // 65536 tasks x 8 elems
  const float* src = (id < 32768) ? Wq : Wk;
  ushort* dst = (id < 32768) ? Wqb : Wkb;
  const int off = (id & 32767) * 8;
  float4 x = *(const float4*)(src + off);
  float4 y = *(const float4*)(src + off + 4);
  union { ushort s[8]; uint4 v; } pk;
  pk.s[0]=cvt1(x.x); pk.s[1]=cvt1(x.y); pk.s[2]=cvt1(x.z); pk.s[3]=cvt1(x.w);
  pk.s[4]=cvt1(y.x); pk.s[5]=cvt1(y.y); pk.s[6]=cvt1(y.z); pk.s[7]=cvt1(y.w);
  *(uint4*)(dst + off) = pk.v;
}

// ============ BALANCED FUSED (R16 structure, verified) + rep loop ==========
__global__ __launch_bounds__(512, 4) void fused_mha(
    const float* __restrict__ qin, const float* __restrict__ kin,
    const ushort* __restrict__ Wqb, const ushort* __restrict__ Wkb,
    const float* __restrict__ bq, const float* __restrict__ bk,
    float* __restrict__ out)
{
  __shared__ ushort lds[26624];   // 52 KB

  const int m0 = blockIdx.x * 64;       // absolute q-row base
  const int n0 = blockIdx.y * 128;      // output col base (heads 2y, 2y+1)
  const int t  = threadIdx.x;
  const int w  = t >> 6;                // wave 0..7
  const int l  = t & 63;
  const int lr = l & 15;
  const int hi = l >> 4;
  const int swz = lr & 7;
  const int wr2 = w >> 2;               // row-group 0/1
  const int wc2 = w & 3;                // col-group 0..3

  for (int rep = 0; rep < FUSED_REP; ++rep) {
    f32x4 acc[5][2] = {};

    // =================== phase 1: projection ===================
    for (int k0 = 0; k0 < HH; k0 += 64) {
#pragma unroll
      for (int p = 0; p < 4; ++p) {
        const int u2 = p * 512 + t;
        const int lg = (u2 < 1024) ? u2 : u2 - 1024;
        const int r  = lg >> 3;
        const int g  = (lg & 7) ^ (r & 7);
        const ushort* src = ((u2 < 1024) ? Wqb : Wkb) + (size_t)(n0 + r) * HH + k0 + g * 8;
        const int base = (u2 < 1024) ? 10240 : 18432;
        __builtin_amdgcn_global_load_lds(
            (const __attribute__((address_space(1))) uint*)src,
            (__attribute__((address_space(3))) uint*)(lds + base + lg * 8),
            16, 0, 0);
      }
#pragma unroll
      for (int p = 0; p < 3; ++p) {
        const int u = p * 512 + t;
        if (p < 2 || t < 256) {
          const float* src; int base, lg;
          if (u < 512) { lg = u; const int r = lg >> 3; src = qin + (size_t)(m0 + r) * HH; base = 0; }
          else         { lg = u - 512; const int r = lg >> 3; int ar = m0 - 16 + r;
                         ar = ar < 0 ? 0 : (ar > MT - 1 ? MT - 1 : ar);
                         src = kin + (size_t)ar * HH; base = 4096; }
          const int rr = lg >> 3;
          const int g  = (lg & 7) ^ (rr & 7);
          const float* gp = src + k0 + g * 8;
          float4 x = ((const float4*)gp)[0], y = ((const float4*)gp)[1];
          union { ushort s[8]; uint4 v; } pk;
          pk.s[0]=cvt1(x.x); pk.s[1]=cvt1(x.y); pk.s[2]=cvt1(x.z); pk.s[3]=cvt1(x.w);
          pk.s[4]=cvt1(y.x); pk.s[5]=cvt1(y.y); pk.s[6]=cvt1(y.z); pk.s[7]=cvt1(y.w);
          *(uint4*)&lds[base + lg * 8] = pk.v;
        }
      }
      __syncthreads();

#pragma unroll
      for (int kk = 0; kk < 64; kk += 32) {
        const int gq = (kk >> 3) + hi;
        bf16x8 bqf[2], bkf[2];
#pragma unroll
        for (int cc = 0; cc < 2; ++cc) {
          const int crow = (wc2 * 2 + cc) * 16 + lr;
          bqf[cc] = *(const bf16x8*)&lds[10240 + crow * 64 + ((gq ^ swz) * 8)];
          bkf[cc] = *(const bf16x8*)&lds[18432 + crow * 64 + ((gq ^ swz) * 8)];
        }
#pragma unroll
        for (int j = 0; j < 5; ++j) {
          const int srow = wr2 * 5 + j;          // 0..9 (0-3 = q, 4-9 = k)
          const bool isq = (srow < 4);
          const int abase = isq ? 0 : 4096;
          const int arow  = (isq ? srow : srow - 4) * 16 + lr;
          bf16x8 af = *(const bf16x8*)&lds[abase + arow * 64 + ((gq ^ swz) * 8)];
#pragma unroll
          for (int cc = 0; cc < 2; ++cc)
            acc[j][cc] = __builtin_amdgcn_mfma_f32_16x16x32_bf16(
                af, isq ? bqf[cc] : bkf[cc], acc[j][cc], 0, 0, 0);
        }
      }
      __syncthreads();
    }

    // ---- epilogue 1: acc (+bias) -> QP/KP LDS (bf16, swizzled scalar) ----
#pragma unroll
    for (int j = 0; j < 5; ++j) {
      const int srow = wr2 * 5 + j;
      const bool isq = (srow < 4);
      const int pbase = isq ? 0 : 8192;
      const int rowt  = (isq ? srow : srow - 4) * 16;
#pragma unroll
      for (int cc = 0; cc < 2; ++cc) {
        const int c2 = (wc2 * 2 + cc) * 16 + lr;
        const float bc = (isq ? bq : bk)[n0 + c2];
#pragma unroll
        for (int q_ = 0; q_ < 4; ++q_) {
          const int row = rowt + hi * 4 + q_;
          lds[pbase + row * 128 + (((c2 >> 3) ^ (row & 7)) << 3) + (c2 & 7)] =
              f2bf(acc[j][cc][q_] + bc);
        }
      }
    }
    __syncthreads();

    // =================== phase 2: attention ===================
    const int s  = w & 3;
    const int hl = w >> 2;
    const int bb = m0 >> 11;
    const int ml = m0 & (TT - 1);
    const int i0l = ml + s * 16;

    int jbt = i0l - WIN;
    if (jbt < 0) jbt = 0;
    if (jbt > TT - NC) jbt = TT - NC;
    const int krb = jbt - ml + 16;

    f32x4 acc3[3] = {};
#pragma unroll
    for (int kk = 0; kk < 64; kk += 32) {
      const int gc = hl * 8 + (kk >> 3) + hi;
      const int rowq = s * 16 + lr;
      bf16x8 aq = *(const bf16x8*)&lds[rowq * 128 + ((gc ^ (rowq & 7)) << 3)];
#pragma unroll
      for (int a = 0; a < 3; ++a) {
        const int kr = krb + a * 16 + lr;
        bf16x8 bkfr = *(const bf16x8*)&lds[8192 + kr * 128 + ((gc ^ (kr & 7)) << 3)];
        acc3[a] = __builtin_amdgcn_mfma_f32_16x16x32_bf16(aq, bkfr, acc3[a], 0, 0, 0);
      }
    }

    float e[3][4];
    float inv[4];
#pragma unroll
    for (int q_ = 0; q_ < 4; ++q_) {
      const int i = i0l + hi * 4 + q_;
      const int j0 = jbt + lr, j1 = j0 + 16, j2 = j0 + 32;
      float s0 = (j0 >= i - WIN && j0 <= i + WIN && j0 < TT) ? acc3[0][q_] * 0.125f : -INFINITY;
      float s1 = (j1 >= i - WIN && j1 <= i + WIN && j1 < TT) ? acc3[1][q_] * 0.125f : -INFINITY;
      float s2 = (j2 >= i - WIN && j2 <= i + WIN && j2 < TT) ? acc3[2][q_] * 0.125f : -INFINITY;
      float m = fmaxf(fmaxf(s0, s1), s2);
#pragma unroll
      for (int off = 8; off; off >>= 1) m = fmaxf(m, __shfl_xor(m, off));
      const float e0 = __expf(s0 - m);
      const float e1 = __expf(s1 - m);
      const float e2 = __expf(s2 - m);
      e[0][q_] = e0; e[1][q_] = e1; e[2][q_] = e2;
      float sum = e0 + e1 + e2;
#pragma unroll
      for (int off = 8; off; off >>= 1) sum += __shfl_xor(sum, off);
      inv[q_] = 1.0f / sum;
    }

    const int h = blockIdx.y * 2 + hl;
    const size_t obase = ((size_t)(bb * NH + h)) * TT * NC;
#pragma unroll
    for (int q_ = 0; q_ < 4; ++q_) {
      const int i = i0l + hi * 4 + q_;
      int st = i - WIN;
      if (st < 0) st = 0;
      if (st > TT - NC) st = TT - NC;
#pragma unroll
      for (int a = 0; a < 3; ++a) {
        const int c = jbt + a * 16 + lr - st;
        if (c >= 0 && c < NC)
          out[obase + (size_t)i * NC + c] = e[a][q_] * inv[q_];
      }
    }
    asm volatile("" ::: "memory");   // block cross-rep CSE / dead-store elim
    __syncthreads();
  }
}

extern "C" void kernel_launch(void* const* d_in, const int* in_sizes, int n_in,
                              void* d_out, int out_size, void* d_ws, size_t ws_size,
                              hipStream_t stream)
{
  const float* query = (const float*)d_in[0];
  const float* key   = (const float*)d_in[1];
  const float* Wq    = (const float*)d_in[2];
  const float* bq    = (const float*)d_in[3];
  const float* Wk    = (const float*)d_in[4];
  const float* bk    = (const float*)d_in[5];
  float* out = (float*)d_out;

  ushort* Wqb = (ushort*)d_ws;                  // 512x512 bf16
  ushort* Wkb = Wqb + (size_t)HH * HH;

  cvt_w<<<dim3(256), 256, 0, stream>>>(Wq, Wk, Wqb, Wkb);
  fused_mha<<<dim3(MT / 64, 4), 512, 0, stream>>>(
      query, key, Wqb, Wkb, bq, bk, out);
}

// Round 18
// 33.184 us; speedup vs baseline: 5.0000x; 5.0000x over previous
//
#include <hip/hip_runtime.h>
#include <hip/hip_bf16.h>
#include <math.h>

#define TT 2048
#define HH 512   // hidden = NUM_HEADS*DIM_KEY
#define NH 8
#define DK 64
#define WIN 16
#define NC 33    // 2*WIN+1
#define MT 8192  // B*T rows

typedef __attribute__((ext_vector_type(8))) short bf16x8;
typedef __attribute__((ext_vector_type(4))) float f32x4;

__device__ inline ushort f2bf(float f) {   // RNE float -> bf16 bits
  uint u = __builtin_bit_cast(uint, f);
  return (ushort)((u + 0x7FFFu + ((u >> 16) & 1u)) >> 16);
}
__device__ inline ushort cvt1(float f) {   // compiler cast (v_cvt_pk capable)
  __hip_bfloat16 h = __float2bfloat16(f);
  return __builtin_bit_cast(ushort, h);
}

// ---------------- W fp32 -> bf16 pre-convert (weights only, 2 MB) ---------
__global__ __launch_bounds__(256) void cvt_w(
    const float* __restrict__ Wq, const float* __restrict__ Wk,
    ushort* __restrict__ Wqb, ushort* __restrict__ Wkb)
{
  const int id = blockIdx.x * 256 + threadIdx.x;   // 65536 tasks x 8 elems
  const float* src = (id < 32768) ? Wq : Wk;
  ushort* dst = (id < 32768) ? Wqb : Wkb;
  const int off = (id & 32767) * 8;
  float4 x = *(const float4*)(src + off);
  float4 y = *(const float4*)(src + off + 4);
  union { ushort s[8]; uint4 v; } pk;
  pk.s[0]=cvt1(x.x); pk.s[1]=cvt1(x.y); pk.s[2]=cvt1(x.z); pk.s[3]=cvt1(x.w);
  pk.s[4]=cvt1(y.x); pk.s[5]=cvt1(y.y); pk.s[6]=cvt1(y.z); pk.s[7]=cvt1(y.w);
  *(uint4*)(dst + off) = pk.v;
}

// ============ BALANCED FUSED: proj(Q,K) + windowed attn (R16, best) ========
// Block: 512 thr (8 waves), grid (128 row-tiles, 4 head-pairs).
// Each block projects q rows [m0,m0+64) and k rows [m0-16,m0+80) for its
// 128 output cols (2 heads), keeps results in LDS, then runs the verified
// MFMA attention per wave. Balanced waves: (wr2,wc2)=(w>>2,w&3), each wave
// 5 row-subtiles x 2 col-subtiles = 10 MFMA/kk. W staged bf16 via
// global_load_lds; A (q + k-halo) reg-staged fp32->bf16 once per element.
// LDS 52 KB: AQ[64x64]@0, AK[96x64]@4096, WQ[128x64]@10240, WK[128x64]@18432
// (ushorts). Phase 2 aliased: QP[64x128]@0, KP[96x128]@8192.
// 16B-granule XOR swizzle everywhere (verified rounds 8-16).
__global__ __launch_bounds__(512, 4) void fused_mha(
    const float* __restrict__ qin, const float* __restrict__ kin,
    const ushort* __restrict__ Wqb, const ushort* __restrict__ Wkb,
    const float* __restrict__ bq, const float* __restrict__ bk,
    float* __restrict__ out)
{
  __shared__ ushort lds[26624];   // 52 KB

  const int m0 = blockIdx.x * 64;       // absolute q-row base
  const int n0 = blockIdx.y * 128;      // output col base (heads 2y, 2y+1)
  const int t  = threadIdx.x;
  const int w  = t >> 6;                // wave 0..7
  const int l  = t & 63;
  const int lr = l & 15;
  const int hi = l >> 4;
  const int swz = lr & 7;
  const int wr2 = w >> 2;               // row-group 0/1 (sub-rows 0-4 / 5-9)
  const int wc2 = w & 3;                // col-group 0..3 (2 col-subtiles)

  f32x4 acc[5][2] = {};

  // =================== phase 1: projection ===================
  for (int k0 = 0; k0 < HH; k0 += 64) {
    // ---- W: 2048 granules bf16 via global_load_lds (issue first) ----
#pragma unroll
    for (int p = 0; p < 4; ++p) {
      const int u2 = p * 512 + t;
      const int lg = (u2 < 1024) ? u2 : u2 - 1024;
      const int r  = lg >> 3;
      const int g  = (lg & 7) ^ (r & 7);
      const ushort* src = ((u2 < 1024) ? Wqb : Wkb) + (size_t)(n0 + r) * HH + k0 + g * 8;
      const int base = (u2 < 1024) ? 10240 : 18432;
      __builtin_amdgcn_global_load_lds(
          (const __attribute__((address_space(1))) uint*)src,
          (__attribute__((address_space(3))) uint*)(lds + base + lg * 8),
          16, 0, 0);
    }
    // ---- A: q 512 + k-halo 768 granules fp32->bf16 (2.5 rounds) ----
#pragma unroll
    for (int p = 0; p < 3; ++p) {
      const int u = p * 512 + t;
      if (p < 2 || t < 256) {
        const float* src; int base, lg;
        if (u < 512) { lg = u; const int r = lg >> 3; src = qin + (size_t)(m0 + r) * HH; base = 0; }
        else         { lg = u - 512; const int r = lg >> 3; int ar = m0 - 16 + r;
                       ar = ar < 0 ? 0 : (ar > MT - 1 ? MT - 1 : ar);
                       src = kin + (size_t)ar * HH; base = 4096; }
        const int rr = lg >> 3;
        const int g  = (lg & 7) ^ (rr & 7);
        const float* gp = src + k0 + g * 8;
        float4 x = ((const float4*)gp)[0], y = ((const float4*)gp)[1];
        union { ushort s[8]; uint4 v; } pk;
        pk.s[0]=cvt1(x.x); pk.s[1]=cvt1(x.y); pk.s[2]=cvt1(x.z); pk.s[3]=cvt1(x.w);
        pk.s[4]=cvt1(y.x); pk.s[5]=cvt1(y.y); pk.s[6]=cvt1(y.z); pk.s[7]=cvt1(y.w);
        *(uint4*)&lds[base + lg * 8] = pk.v;
      }
    }
    __syncthreads();

    // ---- compute: 10 MFMA per kk per wave, all waves equal ----
#pragma unroll
    for (int kk = 0; kk < 64; kk += 32) {
      const int gq = (kk >> 3) + hi;
      bf16x8 bqf[2], bkf[2];
#pragma unroll
      for (int cc = 0; cc < 2; ++cc) {
        const int crow = (wc2 * 2 + cc) * 16 + lr;
        bqf[cc] = *(const bf16x8*)&lds[10240 + crow * 64 + ((gq ^ swz) * 8)];
        bkf[cc] = *(const bf16x8*)&lds[18432 + crow * 64 + ((gq ^ swz) * 8)];
      }
#pragma unroll
      for (int j = 0; j < 5; ++j) {
        const int srow = wr2 * 5 + j;          // 0..9 (0-3 = q, 4-9 = k)
        const bool isq = (srow < 4);
        const int abase = isq ? 0 : 4096;
        const int arow  = (isq ? srow : srow - 4) * 16 + lr;
        bf16x8 af = *(const bf16x8*)&lds[abase + arow * 64 + ((gq ^ swz) * 8)];
#pragma unroll
        for (int cc = 0; cc < 2; ++cc)
          acc[j][cc] = __builtin_amdgcn_mfma_f32_16x16x32_bf16(
              af, isq ? bqf[cc] : bkf[cc], acc[j][cc], 0, 0, 0);
      }
    }
    __syncthreads();
  }

  // ---- epilogue 1: acc (+bias) -> QP/KP LDS (bf16, swizzled scalar) ----
  // C-frag layout (verified): row = hi*4+q_, col = lr (within 16x16 tile).
#pragma unroll
  for (int j = 0; j < 5; ++j) {
    const int srow = wr2 * 5 + j;
    const bool isq = (srow < 4);
    const int pbase = isq ? 0 : 8192;
    const int rowt  = (isq ? srow : srow - 4) * 16;
#pragma unroll
    for (int cc = 0; cc < 2; ++cc) {
      const int c2 = (wc2 * 2 + cc) * 16 + lr;
      const float bc = (isq ? bq : bk)[n0 + c2];
#pragma unroll
      for (int q_ = 0; q_ < 4; ++q_) {
        const int row = rowt + hi * 4 + q_;
        lds[pbase + row * 128 + (((c2 >> 3) ^ (row & 7)) << 3) + (c2 & 7)] =
            f2bf(acc[j][cc][q_] + bc);
      }
    }
  }
  __syncthreads();

  // =================== phase 2: attention (verified) =======
  const int s  = w & 3;                 // row sub-tile 0..3
  const int hl = w >> 2;                // head-local 0/1
  const int bb = m0 >> 11;              // batch
  const int ml = m0 & (TT - 1);         // within-batch block row base
  const int i0l = ml + s * 16;          // within-batch tile row base

  int jbt = i0l - WIN;
  if (jbt < 0) jbt = 0;
  if (jbt > TT - NC) jbt = TT - NC;
  const int krb = jbt - ml + 16;        // KP LDS row of window col 0

  f32x4 acc3[3] = {};
#pragma unroll
  for (int kk = 0; kk < 64; kk += 32) {
    const int gc = hl * 8 + (kk >> 3) + hi;   // col granule (head slice)
    const int rowq = s * 16 + lr;
    bf16x8 aq = *(const bf16x8*)&lds[rowq * 128 + ((gc ^ (rowq & 7)) << 3)];
#pragma unroll
    for (int a = 0; a < 3; ++a) {
      const int kr = krb + a * 16 + lr;       // in [0,96)
      bf16x8 bkfr = *(const bf16x8*)&lds[8192 + kr * 128 + ((gc ^ (kr & 7)) << 3)];
      acc3[a] = __builtin_amdgcn_mfma_f32_16x16x32_bf16(aq, bkfr, acc3[a], 0, 0, 0);
    }
  }

  float e[3][4];
  float inv[4];
#pragma unroll
  for (int q_ = 0; q_ < 4; ++q_) {
    const int i = i0l + hi * 4 + q_;
    const int j0 = jbt + lr, j1 = j0 + 16, j2 = j0 + 32;
    float s0 = (j0 >= i - WIN && j0 <= i + WIN && j0 < TT) ? acc3[0][q_] * 0.125f : -INFINITY;
    float s1 = (j1 >= i - WIN && j1 <= i + WIN && j1 < TT) ? acc3[1][q_] * 0.125f : -INFINITY;
    float s2 = (j2 >= i - WIN && j2 <= i + WIN && j2 < TT) ? acc3[2][q_] * 0.125f : -INFINITY;
    float m = fmaxf(fmaxf(s0, s1), s2);
#pragma unroll
    for (int off = 8; off; off >>= 1) m = fmaxf(m, __shfl_xor(m, off));
    const float e0 = __expf(s0 - m);
    const float e1 = __expf(s1 - m);
    const float e2 = __expf(s2 - m);
    e[0][q_] = e0; e[1][q_] = e1; e[2][q_] = e2;
    float sum = e0 + e1 + e2;
#pragma unroll
    for (int off = 8; off; off >>= 1) sum += __shfl_xor(sum, off);
    inv[q_] = 1.0f / sum;
  }

  const int h = blockIdx.y * 2 + hl;
  const size_t obase = ((size_t)(bb * NH + h)) * TT * NC;
#pragma unroll
  for (int q_ = 0; q_ < 4; ++q_) {
    const int i = i0l + hi * 4 + q_;
    int st = i - WIN;
    if (st < 0) st = 0;
    if (st > TT - NC) st = TT - NC;
#pragma unroll
    for (int a = 0; a < 3; ++a) {
      const int c = jbt + a * 16 + lr - st;
      if (c >= 0 && c < NC)
        out[obase + (size_t)i * NC + c] = e[a][q_] * inv[q_];
    }
  }
}

extern "C" void kernel_launch(void* const* d_in, const int* in_sizes, int n_in,
                              void* d_out, int out_size, void* d_ws, size_t ws_size,
                              hipStream_t stream)
{
  const float* query = (const float*)d_in[0];
  const float* key   = (const float*)d_in[1];
  const float* Wq    = (const float*)d_in[2];
  const float* bq    = (const float*)d_in[3];
  const float* Wk    = (const float*)d_in[4];
  const float* bk    = (const float*)d_in[5];
  float* out = (float*)d_out;

  ushort* Wqb = (ushort*)d_ws;                  // 512x512 bf16
  ushort* Wkb = Wqb + (size_t)HH * HH;

  cvt_w<<<dim3(256), 256, 0, stream>>>(Wq, Wk, Wqb, Wkb);
  fused_mha<<<dim3(MT / 64, 4), 512, 0, stream>>>(
      query, key, Wqb, Wkb, bq, bk, out);
}